// Round 4
// baseline (291.715 us; speedup 1.0000x reference)
//
#include <hip/hip_runtime.h>

#define SEQ 32768
#define QSCALE 0.08838834764831845f

typedef __attribute__((ext_vector_type(8))) short short8;
typedef __attribute__((ext_vector_type(8))) __bf16 bf16x8;
typedef __attribute__((ext_vector_type(16))) float f32x16;
typedef __attribute__((ext_vector_type(4))) float f32x4;
typedef __attribute__((ext_vector_type(4))) int int4v;

// [R][128]-short tile swizzle: XOR short-idx bits 3..5 with row&7 (16B-unit preserving)
#define SWZ(r, c) ((((r) << 7) + (c)) ^ (((r) & 7) << 3))

__device__ __forceinline__ int cvtpk(float lo, float hi) {
  int r;
  asm("v_cvt_pk_bf16_f32 %0, %1, %2" : "=v"(r) : "v"(lo), "v"(hi));
  return r;
}

__device__ __forceinline__ f32x16 mfma_ii(int4v a, int4v b, f32x16 c) {
  return __builtin_amdgcn_mfma_f32_32x32x16_bf16(
      __builtin_bit_cast(bf16x8, a), __builtin_bit_cast(bf16x8, b), c, 0, 0, 0);
}

// C-layout (reg r ↔ n=(r&3)+8*(r>>2)+4*hi, lane) -> A/B frag (reg j ↔ n=hi*8+j)
__device__ __forceinline__ int4v build_frag(float e0, float e1, float e2, float e3,
                                            float e4, float e5, float e6, float e7,
                                            int hi) {
  int t0 = cvtpk(e0, e1), t1 = cvtpk(e2, e3);
  int t2 = cvtpk(e4, e5), t3 = cvtpk(e6, e7);
  const int u0 = __shfl_xor(t2, 32), u1 = __shfl_xor(t3, 32);
  const int u2 = __shfl_xor(t0, 32), u3 = __shfl_xor(t1, 32);
  int4v f;
  f[0] = hi ? u0 : t0;
  f[1] = hi ? u1 : t1;
  f[2] = hi ? t2 : u2;
  f[3] = hi ? t3 : u3;
  return f;
}

// ---------------------------------------------------------------------------
// Prep: W fragment table. Wf[side(q,k,v)][tile4][ks8][lane64] = 16B A/B-frag:
// elem j = W[ks*16+(lane>>5)*8+j][side*128 + tile*32 + (lane&31)]  (bf16)
// ---------------------------------------------------------------------------
__global__ void la_prep(const float* __restrict__ Wqkv, int4v* __restrict__ Wf) {
  const int fid = blockIdx.x * 256 + threadIdx.x;  // 6144 frags
  if (fid >= 6144) return;
  const int side = fid >> 11;
  const int rem = fid & 2047;
  const int tile = rem >> 9;
  const int ks = (rem >> 6) & 7;
  const int lane = rem & 63;
  const int k0 = ks * 16 + ((lane >> 5) << 3);
  const int col = side * 128 + tile * 32 + (lane & 31);
  int4v f;
  #pragma unroll
  for (int a = 0; a < 4; ++a)
    f[a] = cvtpk(Wqkv[(k0 + 2 * a) * 384 + col], Wqkv[(k0 + 2 * a + 1) * 384 + col]);
  Wf[fid] = f;
}

// ---------------------------------------------------------------------------
// Pass 1: q,k proj (o1+o2) + per-side softmax + ctx partial.
// grid 8*strips x 512 thr; 64-row chunks; 2 barriers/chunk.
// ---------------------------------------------------------------------------
__global__ __launch_bounds__(512, 4)
void la_pass1(const float* __restrict__ x, const int4v* __restrict__ Wf,
              float* __restrict__ partials, int strips, int nch) {
  __shared__ __align__(16) short xs[2][64 * 128];       // 32 KB dbuf
  __shared__ int4v fragbuf[2][4][4][64];                // 32 KB [side][tile][ks4][lane]
  __shared__ float sumbuf[2][64][4];                    // 2 KB

  const int tid = threadIdx.x;
  const int lane = tid & 63;
  const int wv = tid >> 6;
  const int l31 = lane & 31;
  const int hi = lane >> 5;
  const int koff = hi << 3;
  const int h = wv >> 2;            // 0=q side, 1=k side
  const int c = wv & 3;             // proj ch-tile
  const int td = wv & 3;            // ctx d-tile
  const int teb = h << 1;           // ctx first e-tile
  const float qs = h ? 1.0f : QSCALE;
  const int b = blockIdx.x / strips;
  const int strip = blockIdx.x - b * strips;
  const long base = (long)b * SEQ + (long)strip * (nch * 64);

  // W fragments for this wave's 32-ch tile (coalesced one-time table load)
  int4v wf[8];
  #pragma unroll
  for (int ks = 0; ks < 8; ++ks)
    wf[ks] = Wf[(((h << 2) + c) * 8 + ks) * 64 + lane];

  const int lr = tid >> 3;            // 0..63
  const int cf = (tid & 7) << 4;      // float col
  {  // preload chunk 0
    const float* xp = x + (base + lr) * 128 + cf;
    f32x4 u0 = *(const f32x4*)xp;
    f32x4 u1 = *(const f32x4*)(xp + 4);
    f32x4 u2 = *(const f32x4*)(xp + 8);
    f32x4 u3 = *(const f32x4*)(xp + 12);
    int4v p0, p1;
    p0[0] = cvtpk(u0[0], u0[1]); p0[1] = cvtpk(u0[2], u0[3]);
    p0[2] = cvtpk(u1[0], u1[1]); p0[3] = cvtpk(u1[2], u1[3]);
    p1[0] = cvtpk(u2[0], u2[1]); p1[1] = cvtpk(u2[2], u2[3]);
    p1[2] = cvtpk(u3[0], u3[1]); p1[3] = cvtpk(u3[2], u3[3]);
    *(int4v*)&xs[0][SWZ(lr, cf)] = p0;
    *(int4v*)&xs[0][SWZ(lr, cf + 8)] = p1;
  }
  __syncthreads();

  f32x16 ctx0 = {0.f}, ctx1 = {0.f};
  int cur = 0;
  for (int ch = 0; ch < nch; ++ch) {
    const int chn = (ch + 1 < nch) ? ch + 1 : ch;
    const float* xp = x + (base + chn * 64 + lr) * 128 + cf;
    f32x4 u0 = *(const f32x4*)xp;
    f32x4 u1 = *(const f32x4*)(xp + 4);
    f32x4 u2 = *(const f32x4*)(xp + 8);
    f32x4 u3 = *(const f32x4*)(xp + 12);

    // o2: P^T (ch in regs, n in lanes) for both 32-row subtiles -> sums
    f32x16 p2a = {0.f}, p2b = {0.f};
    #pragma unroll
    for (int ks = 0; ks < 8; ++ks) {
      const int4v xa = *(const int4v*)&xs[cur][SWZ(l31, ks * 16 + koff)];
      const int4v xb = *(const int4v*)&xs[cur][SWZ(32 + l31, ks * 16 + koff)];
      p2a = mfma_ii(wf[ks], xa, p2a);
      p2b = mfma_ii(wf[ks], xb, p2b);
    }
    float s0 = 0.f, s1 = 0.f;
    #pragma unroll
    for (int r = 0; r < 16; ++r) { s0 += __expf(p2a[r]); s1 += __expf(p2b[r]); }
    s0 += __shfl_xor(s0, 32);
    s1 += __shfl_xor(s1, 32);
    if (!hi) { sumbuf[h][l31][c] = s0; sumbuf[h][32 + l31][c] = s1; }

    // o1: P (n in regs, ch in lanes) -> values
    f32x16 p1a = {0.f}, p1b = {0.f};
    #pragma unroll
    for (int ks = 0; ks < 8; ++ks) {
      const int4v xa = *(const int4v*)&xs[cur][SWZ(l31, ks * 16 + koff)];
      const int4v xb = *(const int4v*)&xs[cur][SWZ(32 + l31, ks * 16 + koff)];
      p1a = mfma_ii(xa, wf[ks], p1a);
      p1b = mfma_ii(xb, wf[ks], p1b);
    }
    float ea[16], eb[16];
    #pragma unroll
    for (int r = 0; r < 16; ++r) { ea[r] = __expf(p1a[r]); eb[r] = __expf(p1b[r]); }

    {  // stage next chunk
      int4v p0, p1;
      p0[0] = cvtpk(u0[0], u0[1]); p0[1] = cvtpk(u0[2], u0[3]);
      p0[2] = cvtpk(u1[0], u1[1]); p0[3] = cvtpk(u1[2], u1[3]);
      p1[0] = cvtpk(u2[0], u2[1]); p1[1] = cvtpk(u2[2], u2[3]);
      p1[2] = cvtpk(u3[0], u3[1]); p1[3] = cvtpk(u3[2], u3[3]);
      *(int4v*)&xs[cur ^ 1][SWZ(lr, cf)] = p0;
      *(int4v*)&xs[cur ^ 1][SWZ(lr, cf + 8)] = p1;
    }
    __syncthreads();                       // B1: sums + stage visible

    // per-side normalization: q *= QSCALE/sq_n ; k *= 1/sk_n
    #pragma unroll
    for (int r = 0; r < 16; ++r) {
      const int n = (r & 3) + ((r >> 2) << 3) + (hi << 2);
      const f32x4 sa = *(const f32x4*)&sumbuf[h][n][0];
      const f32x4 sb = *(const f32x4*)&sumbuf[h][32 + n][0];
      ea[r] *= qs * __builtin_amdgcn_rcpf(sa[0] + sa[1] + sa[2] + sa[3]);
      eb[r] *= qs * __builtin_amdgcn_rcpf(sb[0] + sb[1] + sb[2] + sb[3]);
    }

    fragbuf[h][c][0][lane] = build_frag(ea[0], ea[1], ea[2], ea[3],
                                        ea[4], ea[5], ea[6], ea[7], hi);
    fragbuf[h][c][1][lane] = build_frag(ea[8], ea[9], ea[10], ea[11],
                                        ea[12], ea[13], ea[14], ea[15], hi);
    fragbuf[h][c][2][lane] = build_frag(eb[0], eb[1], eb[2], eb[3],
                                        eb[4], eb[5], eb[6], eb[7], hi);
    fragbuf[h][c][3][lane] = build_frag(eb[8], eb[9], eb[10], eb[11],
                                        eb[12], eb[13], eb[14], eb[15], hi);
    __syncthreads();                       // B2: frags ready

    #pragma unroll
    for (int ks = 0; ks < 4; ++ks) {
      const int4v aq = fragbuf[0][td][ks][lane];
      const int4v bk0 = fragbuf[1][teb][ks][lane];
      const int4v bk1 = fragbuf[1][teb + 1][ks][lane];
      ctx0 = mfma_ii(aq, bk0, ctx0);
      ctx1 = mfma_ii(aq, bk1, ctx1);
    }
    cur ^= 1;
  }

  float* pout = partials + (long)blockIdx.x * 16384;
  #pragma unroll
  for (int r = 0; r < 16; ++r) {
    const int drow = (td << 5) + (r & 3) + ((r >> 2) << 3) + (hi << 2);
    pout[(drow << 7) + (teb << 5) + l31] = ctx0[r];
    pout[(drow << 7) + ((teb + 1) << 5) + l31] = ctx1[r];
  }
}

// ---------------------------------------------------------------------------
// Reduce partials -> ctx[b]   (grid 128 = 8 batches x 16 slices)
// ---------------------------------------------------------------------------
__global__ void la_reduce(const float* __restrict__ partials, float* __restrict__ ctx,
                          int strips) {
  const int b = blockIdx.x >> 4;
  const int sl = blockIdx.x & 15;
  const int idx = (sl << 10) + ((int)threadIdx.x << 2);
  f32x4 acc = {0.f};
  for (int st = 0; st < strips; ++st)
    acc += *(const f32x4*)(partials + ((long)(b * strips + st) << 14) + idx);
  *(f32x4*)(ctx + ((long)b << 14) + idx) = acc;
}

// ---------------------------------------------------------------------------
// Mt = (ctx^T W_out)^T stored as MFMA B-frag table:
// Mtf[b][dt][ks][lane] 16B: elem j = Mt[dt*32+(lane&31)][ks*16+(lane>>5)*8+j]
// ---------------------------------------------------------------------------
__global__ void la_mkern(const float* __restrict__ ctx, const float* __restrict__ Wout,
                         int4v* __restrict__ Mtf) {
  __shared__ __align__(16) float cl[128 * 132];
  __shared__ float wo[128 * 32];
  const int tid = threadIdx.x;
  const int b = blockIdx.x >> 2;
  const int d0 = (blockIdx.x & 3) << 5;
  const float* cp = ctx + ((long)b << 14);
  for (int i = tid << 2; i < 16384; i += 1024) {
    f32x4 v = *(const f32x4*)(cp + i);
    *(f32x4*)&cl[(i >> 7) * 132 + (i & 127)] = v;
  }
  for (int i = tid; i < 128 * 32; i += 256)
    wo[i] = Wout[((i >> 5) << 7) + d0 + (i & 31)];
  __syncthreads();
  const int dq = tid >> 3;            // d' within [0,32)
  const int e0 = (tid & 7) << 4;
  float acc[16];
  #pragma unroll
  for (int i = 0; i < 16; ++i) acc[i] = 0.0f;
  for (int d = 0; d < 128; ++d) {
    const float w = wo[(d << 5) + dq];
    const float* cr = &cl[d * 132 + e0];
    #pragma unroll
    for (int i = 0; i < 16; ++i) acc[i] += cr[i] * w;
  }
  const int dp = d0 + dq;             // global d'
  const int dt = dp >> 5, l = dp & 31, ks = e0 >> 4;
  int4v lo, hi2;
  lo[0] = cvtpk(acc[0], acc[1]);  lo[1] = cvtpk(acc[2], acc[3]);
  lo[2] = cvtpk(acc[4], acc[5]);  lo[3] = cvtpk(acc[6], acc[7]);
  hi2[0] = cvtpk(acc[8], acc[9]);  hi2[1] = cvtpk(acc[10], acc[11]);
  hi2[2] = cvtpk(acc[12], acc[13]); hi2[3] = cvtpk(acc[14], acc[15]);
  Mtf[(((b << 2) + dt) * 8 + ks) * 64 + l] = lo;
  Mtf[(((b << 2) + dt) * 8 + ks) * 64 + 32 + l] = hi2;
}

// ---------------------------------------------------------------------------
// Pass 2: one 128-row chunk per block; 4 waves x 32 rows; ONE barrier.
// Stage x->LDS (coalesced); o2 v-proj (lane-local softmax); out-GEMM with
// W/Mt frags streamed from L2; coalesced f32 stores.
// ---------------------------------------------------------------------------
__global__ __launch_bounds__(256, 4)
void la_pass2(const float* __restrict__ x, const int4v* __restrict__ Wf,
              const int4v* __restrict__ Mtf, const float* __restrict__ bout,
              float* __restrict__ out) {
  __shared__ __align__(16) short xs[128 * 128];   // 32 KB

  const int tid = threadIdx.x;
  const int lane = tid & 63;
  const int wv = tid >> 6;
  const int l31 = lane & 31;
  const int hi = lane >> 5;
  const int koff = hi << 3;
  const int b = blockIdx.x >> 8;
  const int chunk = blockIdx.x & 255;
  const long row0 = (long)b * SEQ + (long)chunk * 128;

  {  // stage 128x128 f32 -> bf16 LDS, 64B/thread segments, coalesced
    const int row = tid >> 1;
    const int cb = (tid & 1) << 6;
    const float* xp = x + (row0 + row) * 128 + cb;
    #pragma unroll
    for (int s = 0; s < 4; ++s) {
      f32x4 u0 = *(const f32x4*)(xp + s * 16);
      f32x4 u1 = *(const f32x4*)(xp + s * 16 + 4);
      f32x4 u2 = *(const f32x4*)(xp + s * 16 + 8);
      f32x4 u3 = *(const f32x4*)(xp + s * 16 + 12);
      int4v p0, p1;
      p0[0] = cvtpk(u0[0], u0[1]); p0[1] = cvtpk(u0[2], u0[3]);
      p0[2] = cvtpk(u1[0], u1[1]); p0[3] = cvtpk(u1[2], u1[3]);
      p1[0] = cvtpk(u2[0], u2[1]); p1[1] = cvtpk(u2[2], u2[3]);
      p1[2] = cvtpk(u3[0], u3[1]); p1[3] = cvtpk(u3[2], u3[3]);
      *(int4v*)&xs[SWZ(row, cb + s * 16)] = p0;
      *(int4v*)&xs[SWZ(row, cb + s * 16 + 8)] = p1;
    }
  }
  float bias[4];
  #pragma unroll
  for (int dt = 0; dt < 4; ++dt) bias[dt] = bout[dt * 32 + l31];
  __syncthreads();

  // x fragments for this wave's 32 rows
  int4v xfr[8];
  #pragma unroll
  for (int ks = 0; ks < 8; ++ks)
    xfr[ks] = *(const int4v*)&xs[SWZ((wv << 5) + l31, ks * 16 + koff)];

  // v-proj o2: C[ch in regs][n=l31], 4 ch-tiles; W-frags from L2 table
  const int4v* WvT = Wf + 2 * 2048;   // side 2 (v)
  f32x16 a0 = {0.f}, a1 = {0.f}, a2 = {0.f}, a3 = {0.f};
  #pragma unroll
  for (int ks = 0; ks < 8; ++ks) {
    a0 = mfma_ii(WvT[(0 * 8 + ks) * 64 + lane], xfr[ks], a0);
    a1 = mfma_ii(WvT[(1 * 8 + ks) * 64 + lane], xfr[ks], a1);
    a2 = mfma_ii(WvT[(2 * 8 + ks) * 64 + lane], xfr[ks], a2);
    a3 = mfma_ii(WvT[(3 * 8 + ks) * 64 + lane], xfr[ks], a3);
  }

  // softmax: fully lane-local sum over 128 channels
  float s = 0.f;
  #pragma unroll
  for (int r = 0; r < 16; ++r) {
    a0[r] = __expf(a0[r]); s += a0[r];
    a1[r] = __expf(a1[r]); s += a1[r];
    a2[r] = __expf(a2[r]); s += a2[r];
    a3[r] = __expf(a3[r]); s += a3[r];
  }
  s += __shfl_xor(s, 32);
  const float inv = __builtin_amdgcn_rcpf(s);
  #pragma unroll
  for (int r = 0; r < 16; ++r) {
    a0[r] *= inv; a1[r] *= inv; a2[r] *= inv; a3[r] *= inv;
  }

  // A-frags for out-GEMM (K = e)
  int4v vf[8];
  vf[0] = build_frag(a0[0], a0[1], a0[2], a0[3], a0[4], a0[5], a0[6], a0[7], hi);
  vf[1] = build_frag(a0[8], a0[9], a0[10], a0[11], a0[12], a0[13], a0[14], a0[15], hi);
  vf[2] = build_frag(a1[0], a1[1], a1[2], a1[3], a1[4], a1[5], a1[6], a1[7], hi);
  vf[3] = build_frag(a1[8], a1[9], a1[10], a1[11], a1[12], a1[13], a1[14], a1[15], hi);
  vf[4] = build_frag(a2[0], a2[1], a2[2], a2[3], a2[4], a2[5], a2[6], a2[7], hi);
  vf[5] = build_frag(a2[8], a2[9], a2[10], a2[11], a2[12], a2[13], a2[14], a2[15], hi);
  vf[6] = build_frag(a3[0], a3[1], a3[2], a3[3], a3[4], a3[5], a3[6], a3[7], hi);
  vf[7] = build_frag(a3[8], a3[9], a3[10], a3[11], a3[12], a3[13], a3[14], a3[15], hi);

  // out[n][d'] = v @ Mt^T + bias ; Mt B-frags from L2 table
  const int4v* MtB = Mtf + (long)b * 2048;
  float* obase = out + (row0 + (wv << 5)) * 128;
  #pragma unroll
  for (int dt = 0; dt < 4; ++dt) {
    f32x16 o = {0.f};
    #pragma unroll
    for (int ks = 0; ks < 8; ++ks)
      o = mfma_ii(vf[ks], MtB[(dt * 8 + ks) * 64 + lane], o);
    float* op = obase + dt * 32 + l31;
    #pragma unroll
    for (int r = 0; r < 16; ++r)
      op[((r & 3) + ((r >> 2) << 3) + (hi << 2)) * 128] = o[r] + bias[dt];
  }
}

extern "C" void kernel_launch(void* const* d_in, const int* in_sizes, int n_in,
                              void* d_out, int out_size, void* d_ws, size_t ws_size,
                              hipStream_t stream) {
  const float* x = (const float*)d_in[0];
  const float* Wqkv = (const float*)d_in[1];
  const float* Wout = (const float*)d_in[2];
  const float* bout = (const float*)d_in[3];
  float* out = (float*)d_out;

  const size_t need64 = (size_t)512 * 16384 * 4 + (size_t)8 * 16384 * 4 +
                        (size_t)16384 * 16 + (size_t)6144 * 16;
  const int strips = (ws_size >= need64) ? 64 : 32;
  const int nch = SEQ / (strips * 64);

  float* partials = (float*)d_ws;                        // 8*strips * 16384 f32
  float* ctx = partials + (size_t)8 * strips * 16384;    // 8 * 16384 f32
  int4v* Mtf = (int4v*)(ctx + 8 * 16384);                // 16384 int4v (256 KB)
  int4v* Wf = Mtf + 16384;                               // 6144 int4v (96 KB)

  la_prep<<<dim3(24), dim3(256), 0, stream>>>(Wqkv, Wf);
  la_pass1<<<dim3(8 * strips), dim3(512), 0, stream>>>(x, Wf, partials, strips, nch);
  la_reduce<<<dim3(128), dim3(256), 0, stream>>>(partials, ctx, strips);
  la_mkern<<<dim3(32), dim3(256), 0, stream>>>(ctx, Wout, Mtf);
  la_pass2<<<dim3(2048), dim3(256), 0, stream>>>(x, Wf, Mtf, bout, out);
}

// Round 6
// 188.132 us; speedup vs baseline: 1.5506x; 1.5506x over previous
//
#include <hip/hip_runtime.h>

#define SEQ 32768
#define QSCALE 0.08838834764831845f

typedef __attribute__((ext_vector_type(8))) short short8;
typedef __attribute__((ext_vector_type(8))) __bf16 bf16x8;
typedef __attribute__((ext_vector_type(16))) float f32x16;
typedef __attribute__((ext_vector_type(4))) float f32x4;
typedef __attribute__((ext_vector_type(4))) int int4v;

// [R][128]-short tile swizzle: XOR short-idx bits 3..5 with row&7 (16B-unit preserving)
#define SWZ(r, c) ((((r) << 7) + (c)) ^ (((r) & 7) << 3))

__device__ __forceinline__ int cvtpk(float lo, float hi) {
  int r;
  asm("v_cvt_pk_bf16_f32 %0, %1, %2" : "=v"(r) : "v"(lo), "v"(hi));
  return r;
}

__device__ __forceinline__ f32x16 mfma_ii(int4v a, int4v b, f32x16 c) {
  return __builtin_amdgcn_mfma_f32_32x32x16_bf16(
      __builtin_bit_cast(bf16x8, a), __builtin_bit_cast(bf16x8, b), c, 0, 0, 0);
}

// C-layout (reg r <-> n=(r&3)+8*(r>>2)+4*hi, lane) -> A/B frag (reg j <-> n=hi*8+j)
__device__ __forceinline__ int4v build_frag(float e0, float e1, float e2, float e3,
                                            float e4, float e5, float e6, float e7,
                                            int hi) {
  int t0 = cvtpk(e0, e1), t1 = cvtpk(e2, e3);
  int t2 = cvtpk(e4, e5), t3 = cvtpk(e6, e7);
  const int u0 = __shfl_xor(t2, 32), u1 = __shfl_xor(t3, 32);
  const int u2 = __shfl_xor(t0, 32), u3 = __shfl_xor(t1, 32);
  int4v f;
  f[0] = hi ? u0 : t0;
  f[1] = hi ? u1 : t1;
  f[2] = hi ? t2 : u2;
  f[3] = hi ? t3 : u3;
  return f;
}

// ---------------------------------------------------------------------------
// Prep: W fragment table. Wf[side(q,k,v)][tile4][ks8][lane64] = 16B A/B-frag:
// elem j = W[ks*16+(lane>>5)*8+j][side*128 + tile*32 + (lane&31)]  (bf16)
// ---------------------------------------------------------------------------
__global__ void la_prep(const float* __restrict__ Wqkv, int4v* __restrict__ Wf) {
  const int fid = blockIdx.x * 256 + threadIdx.x;  // 6144 frags
  if (fid >= 6144) return;
  const int side = fid >> 11;
  const int rem = fid & 2047;
  const int tile = rem >> 9;
  const int ks = (rem >> 6) & 7;
  const int lane = rem & 63;
  const int k0 = ks * 16 + ((lane >> 5) << 3);
  const int col = side * 128 + tile * 32 + (lane & 31);
  int4v f;
  #pragma unroll
  for (int a = 0; a < 4; ++a)
    f[a] = cvtpk(Wqkv[(k0 + 2 * a) * 384 + col], Wqkv[(k0 + 2 * a + 1) * 384 + col]);
  Wf[fid] = f;
}

// ---------------------------------------------------------------------------
// Pass 1: q,k proj (o1+o2) + per-side softmax + ctx partial.
// Round-3-proven sync skeleton: 32-row chunks, 2 barriers/chunk, immediate ctx,
// single-buffered fragbuf/sumbuf. Deltas: Wf table load, per-side norm.
// ---------------------------------------------------------------------------
__global__ __launch_bounds__(512, 4)
void la_pass1(const float* __restrict__ x, const int4v* __restrict__ Wf,
              float* __restrict__ partials, int strips, int nch) {
  __shared__ __align__(16) short xs[2][32 * 128];   // 16 KB dbuf
  __shared__ int4v fragbuf[16][64];                 // 16 KB (q:0-7, k:8-15)
  __shared__ __align__(16) float sumbuf[2][32][4];  // 1 KB [side][n][tile]

  const int tid = threadIdx.x;
  const int lane = tid & 63;
  const int wv = tid >> 6;
  const int l31 = lane & 31;
  const int hi = lane >> 5;
  const int koff = hi << 3;
  const int h = wv >> 2;            // 0=q side, 1=k side
  const int c = wv & 3;             // proj ch-tile
  const int td = wv & 3;            // ctx d-tile
  const int teb = h << 1;           // ctx first e-tile
  const float qs = h ? 1.0f : QSCALE;
  const int b = blockIdx.x / strips;
  const int strip = blockIdx.x - b * strips;
  const long base = (long)b * SEQ + (long)strip * (nch * 32);

  // W fragments for this wave's 32-ch tile (coalesced one-time table load)
  int4v wf[8];
  #pragma unroll
  for (int ks = 0; ks < 8; ++ks)
    wf[ks] = Wf[((((h << 2) + c) << 3) + ks) * 64 + lane];

  const int lr = tid >> 4;          // 0..31
  const int cf = (tid & 15) << 3;   // float col
  {  // preload chunk 0
    const float* xp = x + (base + lr) * 128 + cf;
    f32x4 u0 = *(const f32x4*)xp;
    f32x4 u1 = *(const f32x4*)(xp + 4);
    int4v p;
    p[0] = cvtpk(u0[0], u0[1]); p[1] = cvtpk(u0[2], u0[3]);
    p[2] = cvtpk(u1[0], u1[1]); p[3] = cvtpk(u1[2], u1[3]);
    *(int4v*)&xs[0][SWZ(lr, cf)] = p;
  }
  __syncthreads();

  f32x16 ctx0 = {0.f}, ctx1 = {0.f};
  for (int i = 0; i < nch; ++i) {
    const int cur = i & 1;
    const int inx = (i + 1 < nch) ? i + 1 : i;
    const float* xp = x + (base + inx * 32 + lr) * 128 + cf;
    f32x4 u0 = *(const f32x4*)xp;
    f32x4 u1 = *(const f32x4*)(xp + 4);

    // projection both orientations from the same LDS fragment reads
    f32x16 po1 = {0.f}, po2 = {0.f};
    #pragma unroll
    for (int ks = 0; ks < 8; ++ks) {
      const int4v xf = *(const int4v*)&xs[cur][SWZ(l31, (ks << 4) + koff)];
      po1 = mfma_ii(xf, wf[ks], po1);   // P[n in regs][ch in lanes]
      po2 = mfma_ii(wf[ks], xf, po2);   // P^T[ch in regs][n in lanes]
    }

    // o2 sums: lane-local over 16 channel-regs + cross-half
    float s = 0.f;
    #pragma unroll
    for (int r = 0; r < 16; ++r) s += __expf(po2[r]);
    s += __shfl_xor(s, 32);
    if (!hi) sumbuf[h][l31][c] = s;

    // o1 exp (values)
    float e1[16];
    #pragma unroll
    for (int r = 0; r < 16; ++r) e1[r] = __expf(po1[r]);

    {  // stage next chunk
      int4v p;
      p[0] = cvtpk(u0[0], u0[1]); p[1] = cvtpk(u0[2], u0[3]);
      p[2] = cvtpk(u1[0], u1[1]); p[3] = cvtpk(u1[2], u1[3]);
      *(int4v*)&xs[cur ^ 1][SWZ(lr, cf)] = p;
    }
    __syncthreads();                    // B1: sums + stage visible

    // per-side normalization: q *= QSCALE/sq_n ; k *= 1/sk_n
    #pragma unroll
    for (int r = 0; r < 16; ++r) {
      const int n = (r & 3) + ((r >> 2) << 3) + (hi << 2);
      const f32x4 sv = *(const f32x4*)&sumbuf[h][n][0];
      e1[r] *= qs * __builtin_amdgcn_rcpf(sv[0] + sv[1] + sv[2] + sv[3]);
    }

    fragbuf[(h << 3) + (c << 1) + 0][lane] = build_frag(e1[0], e1[1], e1[2], e1[3],
                                                        e1[4], e1[5], e1[6], e1[7], hi);
    fragbuf[(h << 3) + (c << 1) + 1][lane] = build_frag(e1[8], e1[9], e1[10], e1[11],
                                                        e1[12], e1[13], e1[14], e1[15], hi);
    __syncthreads();                    // B2: frags ready

    // ctx += q^T k (immediate, same iteration — round-3 proven)
    #pragma unroll
    for (int ks = 0; ks < 2; ++ks) {
      const int4v aq = fragbuf[(td << 1) + ks][lane];
      ctx0 = mfma_ii(aq, fragbuf[8 + (teb << 1) + ks][lane], ctx0);
      ctx1 = mfma_ii(aq, fragbuf[8 + ((teb + 1) << 1) + ks][lane], ctx1);
    }
  }

  float* pout = partials + (long)blockIdx.x * 16384;
  #pragma unroll
  for (int r = 0; r < 16; ++r) {
    const int drow = (td << 5) + (r & 3) + ((r >> 2) << 3) + (hi << 2);
    pout[(drow << 7) + (teb << 5) + l31] = ctx0[r];
    pout[(drow << 7) + ((teb + 1) << 5) + l31] = ctx1[r];
  }
}

// ---------------------------------------------------------------------------
// Reduce partials -> ctx[b]   (grid 128 = 8 batches x 16 slices)
// ---------------------------------------------------------------------------
__global__ void la_reduce(const float* __restrict__ partials, float* __restrict__ ctx,
                          int strips) {
  const int b = blockIdx.x >> 4;
  const int sl = blockIdx.x & 15;
  const int idx = (sl << 10) + ((int)threadIdx.x << 2);
  f32x4 acc = {0.f};
  for (int st = 0; st < strips; ++st)
    acc += *(const f32x4*)(partials + ((long)(b * strips + st) << 14) + idx);
  *(f32x4*)(ctx + ((long)b << 14) + idx) = acc;
}

// ---------------------------------------------------------------------------
// Mt = (ctx^T W_out)^T stored as interleaved-column MFMA B-frag table:
// Mtf[b][j4][ks8][lane] 16B: elem m = Mt[4*(lane&31)+j][ks*16+(lane>>5)*8+m]
// (column d' = 4*l31+j so pass2 stores f32x4 per lane, fully coalesced)
// ---------------------------------------------------------------------------
__global__ void la_mkern(const float* __restrict__ ctx, const float* __restrict__ Wout,
                         int4v* __restrict__ Mtf) {
  __shared__ __align__(16) float cl[128 * 132];
  __shared__ float wo[128 * 32];
  const int tid = threadIdx.x;
  const int b = blockIdx.x >> 2;
  const int d0 = (blockIdx.x & 3) << 5;
  const float* cp = ctx + ((long)b << 14);
  for (int i = tid << 2; i < 16384; i += 1024) {
    f32x4 v = *(const f32x4*)(cp + i);
    *(f32x4*)&cl[(i >> 7) * 132 + (i & 127)] = v;
  }
  for (int i = tid; i < 128 * 32; i += 256)
    wo[i] = Wout[((i >> 5) << 7) + d0 + (i & 31)];
  __syncthreads();
  const int dq = tid >> 3;            // d' within [0,32)
  const int e0 = (tid & 7) << 4;
  float acc[16];
  #pragma unroll
  for (int i = 0; i < 16; ++i) acc[i] = 0.0f;
  for (int d = 0; d < 128; ++d) {
    const float w = wo[(d << 5) + dq];
    const float* cr = &cl[d * 132 + e0];
    #pragma unroll
    for (int i = 0; i < 16; ++i) acc[i] += cr[i] * w;
  }
  const int dp = d0 + dq;             // global d'
  const int j = dp & 3, l = dp >> 2, ks = e0 >> 4;
  int4v lo, hi2;
  lo[0] = cvtpk(acc[0], acc[1]);   lo[1] = cvtpk(acc[2], acc[3]);
  lo[2] = cvtpk(acc[4], acc[5]);   lo[3] = cvtpk(acc[6], acc[7]);
  hi2[0] = cvtpk(acc[8], acc[9]);  hi2[1] = cvtpk(acc[10], acc[11]);
  hi2[2] = cvtpk(acc[12], acc[13]); hi2[3] = cvtpk(acc[14], acc[15]);
  int4v* dst = Mtf + ((((long)b << 2) + j) * 8 + ks) * 64;
  dst[l] = lo;
  dst[32 + l] = hi2;
}

// ---------------------------------------------------------------------------
// Pass 2: round-4-proven flow (stage -> o2 proj -> f32 normalize -> frags ->
// out-GEMM), one barrier. New: interleaved Mt table -> coalesced f32x4 stores.
// grid 2048 = 8 batches x 256 chunks of 128 rows; 256 thr (4 waves x 32 rows).
// ---------------------------------------------------------------------------
__global__ __launch_bounds__(256, 3)
void la_pass2(const float* __restrict__ x, const int4v* __restrict__ Wf,
              const int4v* __restrict__ Mtf, const float* __restrict__ bout,
              float* __restrict__ out) {
  __shared__ __align__(16) short xs[128 * 128];   // 32 KB

  const int tid = threadIdx.x;
  const int lane = tid & 63;
  const int wv = tid >> 6;
  const int l31 = lane & 31;
  const int hi = lane >> 5;
  const int koff = hi << 3;
  const int b = blockIdx.x >> 8;
  const int chunk = blockIdx.x & 255;
  const long row0 = (long)b * SEQ + (long)chunk * 128;

  {  // stage 128x128 f32 -> bf16 LDS, 64B/thread segments (round-4 proven)
    const int row = tid >> 1;
    const int cb = (tid & 1) << 6;
    const float* xp = x + (row0 + row) * 128 + cb;
    #pragma unroll
    for (int s = 0; s < 4; ++s) {
      f32x4 u0 = *(const f32x4*)(xp + s * 16);
      f32x4 u1 = *(const f32x4*)(xp + s * 16 + 4);
      f32x4 u2 = *(const f32x4*)(xp + s * 16 + 8);
      f32x4 u3 = *(const f32x4*)(xp + s * 16 + 12);
      int4v p0, p1;
      p0[0] = cvtpk(u0[0], u0[1]); p0[1] = cvtpk(u0[2], u0[3]);
      p0[2] = cvtpk(u1[0], u1[1]); p0[3] = cvtpk(u1[2], u1[3]);
      p1[0] = cvtpk(u2[0], u2[1]); p1[1] = cvtpk(u2[2], u2[3]);
      p1[2] = cvtpk(u3[0], u3[1]); p1[3] = cvtpk(u3[2], u3[3]);
      *(int4v*)&xs[SWZ(row, cb + s * 16)] = p0;
      *(int4v*)&xs[SWZ(row, cb + s * 16 + 8)] = p1;
    }
  }
  const f32x4 bias = *(const f32x4*)(bout + (l31 << 2));   // d' = 4*l31+j
  __syncthreads();   // only barrier

  // x fragments for this wave's 32 rows
  int4v xfr[8];
  #pragma unroll
  for (int ks = 0; ks < 8; ++ks)
    xfr[ks] = *(const int4v*)&xs[SWZ((wv << 5) + l31, (ks << 4) + koff)];

  // v-proj o2: C[ch in regs][n=l31], 4 ch-tiles; W-frags from L2 table
  const int4v* WvT = Wf + 2 * 2048;   // side 2 (v)
  f32x16 a0 = {0.f}, a1 = {0.f}, a2 = {0.f}, a3 = {0.f};
  #pragma unroll
  for (int ks = 0; ks < 8; ++ks) {
    a0 = mfma_ii(WvT[(0 * 8 + ks) * 64 + lane], xfr[ks], a0);
    a1 = mfma_ii(WvT[(1 * 8 + ks) * 64 + lane], xfr[ks], a1);
    a2 = mfma_ii(WvT[(2 * 8 + ks) * 64 + lane], xfr[ks], a2);
    a3 = mfma_ii(WvT[(3 * 8 + ks) * 64 + lane], xfr[ks], a3);
  }

  // softmax: fully lane-local sum over 128 channels, normalize in f32
  float s = 0.f;
  #pragma unroll
  for (int r = 0; r < 16; ++r) {
    a0[r] = __expf(a0[r]); s += a0[r];
    a1[r] = __expf(a1[r]); s += a1[r];
    a2[r] = __expf(a2[r]); s += a2[r];
    a3[r] = __expf(a3[r]); s += a3[r];
  }
  s += __shfl_xor(s, 32);
  const float inv = __builtin_amdgcn_rcpf(s);
  #pragma unroll
  for (int r = 0; r < 16; ++r) {
    a0[r] *= inv; a1[r] *= inv; a2[r] *= inv; a3[r] *= inv;
  }

  // A-frags for out-GEMM (K = e)
  int4v vf[8];
  vf[0] = build_frag(a0[0], a0[1], a0[2], a0[3], a0[4], a0[5], a0[6], a0[7], hi);
  vf[1] = build_frag(a0[8], a0[9], a0[10], a0[11], a0[12], a0[13], a0[14], a0[15], hi);
  vf[2] = build_frag(a1[0], a1[1], a1[2], a1[3], a1[4], a1[5], a1[6], a1[7], hi);
  vf[3] = build_frag(a1[8], a1[9], a1[10], a1[11], a1[12], a1[13], a1[14], a1[15], hi);
  vf[4] = build_frag(a2[0], a2[1], a2[2], a2[3], a2[4], a2[5], a2[6], a2[7], hi);
  vf[5] = build_frag(a2[8], a2[9], a2[10], a2[11], a2[12], a2[13], a2[14], a2[15], hi);
  vf[6] = build_frag(a3[0], a3[1], a3[2], a3[3], a3[4], a3[5], a3[6], a3[7], hi);
  vf[7] = build_frag(a3[8], a3[9], a3[10], a3[11], a3[12], a3[13], a3[14], a3[15], hi);

  // out[n][d'] = v @ Mt^T + bias ; interleaved Mt B-frags (col c <-> d'=4c+j)
  const int4v* MtB = Mtf + ((long)b << 11);
  f32x16 o0 = {0.f}, o1 = {0.f}, o2 = {0.f}, o3 = {0.f};
  #pragma unroll
  for (int ks = 0; ks < 8; ++ks) {
    o0 = mfma_ii(vf[ks], MtB[(0 * 8 + ks) * 64 + lane], o0);
    o1 = mfma_ii(vf[ks], MtB[(1 * 8 + ks) * 64 + lane], o1);
    o2 = mfma_ii(vf[ks], MtB[(2 * 8 + ks) * 64 + lane], o2);
    o3 = mfma_ii(vf[ks], MtB[(3 * 8 + ks) * 64 + lane], o3);
  }

  float* obase = out + (row0 + (wv << 5)) * 128 + (l31 << 2);
  #pragma unroll
  for (int r = 0; r < 16; ++r) {
    const int n = (r & 3) + ((r >> 2) << 3) + (hi << 2);
    f32x4 v;
    v[0] = o0[r] + bias[0];
    v[1] = o1[r] + bias[1];
    v[2] = o2[r] + bias[2];
    v[3] = o3[r] + bias[3];
    *(f32x4*)(obase + (long)n * 128) = v;
  }
}

extern "C" void kernel_launch(void* const* d_in, const int* in_sizes, int n_in,
                              void* d_out, int out_size, void* d_ws, size_t ws_size,
                              hipStream_t stream) {
  const float* x = (const float*)d_in[0];
  const float* Wqkv = (const float*)d_in[1];
  const float* Wout = (const float*)d_in[2];
  const float* bout = (const float*)d_in[3];
  float* out = (float*)d_out;

  const size_t need64 = (size_t)512 * 16384 * 4 + (size_t)8 * 16384 * 4 +
                        (size_t)16384 * 16 + (size_t)6144 * 16;
  const int strips = (ws_size >= need64) ? 64 : 32;
  const int nch = SEQ / (strips * 32);

  float* partials = (float*)d_ws;                        // 8*strips * 16384 f32
  float* ctx = partials + (size_t)8 * strips * 16384;    // 8 * 16384 f32
  int4v* Mtf = (int4v*)(ctx + 8 * 16384);                // 16384 int4v (256 KB)
  int4v* Wf = Mtf + 16384;                               // 6144 int4v (96 KB)

  la_prep<<<dim3(24), dim3(256), 0, stream>>>(Wqkv, Wf);
  la_pass1<<<dim3(8 * strips), dim3(512), 0, stream>>>(x, Wf, partials, strips, nch);
  la_reduce<<<dim3(128), dim3(256), 0, stream>>>(partials, ctx, strips);
  la_mkern<<<dim3(32), dim3(256), 0, stream>>>(ctx, Wout, Mtf);
  la_pass2<<<dim3(2048), dim3(256), 0, stream>>>(x, Wf, Mtf, bout, out);
}